// Round 6
// baseline (116.666 us; speedup 1.0000x reference)
//
#include <hip/hip_runtime.h>

// Problem dims (fixed by reference setup_inputs)
#define BDIM 256
#define IDIM 1024
#define ODIM 1024

#define NW2 16               // waves per block (i-split 16 x 64)
#define QL2 64               // i per wave
#define NP2 32               // v2f i-pairs per lane
#define NO2 8                // outputs per block

typedef float v2f __attribute__((ext_vector_type(2)));
typedef float v4f __attribute__((ext_vector_type(4)));

#if __has_builtin(__builtin_amdgcn_exp2f)
#define FAST_EXP2(v) __builtin_amdgcn_exp2f(v)
#else
#define FAST_EXP2(v) exp2f(v)
#endif

// Scalarize a pointer: readfirstlane both halves so the compiler PROVES
// uniformity and selects s_load for loads off it (SGPR stream, zero VMEM).
__device__ __forceinline__ const float* uptr(const float* p) {
  unsigned long long v = (unsigned long long)p;
  unsigned lo = __builtin_amdgcn_readfirstlane((unsigned)v);
  unsigned hi = __builtin_amdgcn_readfirstlane((unsigned)(v >> 32));
  return (const float*)(((unsigned long long)hi << 32) | lo);
}

// ---------------------------------------------------------------------------
// Prep: wS[e][o][i'] = log2e * w[e*64+i'][o]  (e = i>>6)   [4 MB]
//       xT[i][b]     = x[b][i]                              [1 MB]
// 1280 blocks x 256 threads, 32x32 LDS tiles (padded, conflict-free),
// coalesced on both sides. ~10 MB traffic ≈ 3 µs.
// ---------------------------------------------------------------------------
__global__ __launch_bounds__(256)
void prep2(const float* __restrict__ x, const float* __restrict__ w,
           float* __restrict__ wS, float* __restrict__ xT) {
  __shared__ float lt[32][33];
  const int tid = threadIdx.x;
  const float LOG2E = 1.4426950408889634f;
  const int t = blockIdx.x;
  if (t < 1024) {                       // w: 32x32 tiles, 32x32 grid
    const int i0 = (t >> 5) * 32, o0 = (t & 31) * 32;
#pragma unroll
    for (int k = 0; k < 4; ++k) {
      int idx = tid + k * 256, r = idx >> 5, c = idx & 31;   // r:i c:o
      lt[r][c] = LOG2E * w[(size_t)(i0 + r) * ODIM + o0 + c];
    }
    __syncthreads();
    const int e = i0 >> 6, ib = i0 & 63;
#pragma unroll
    for (int k = 0; k < 4; ++k) {
      int idx = tid + k * 256, orr = idx >> 5, ir = idx & 31; // ir fast: coalesced
      wS[(size_t)e * (ODIM * QL2) + (size_t)(o0 + orr) * QL2 + ib + ir] = lt[ir][orr];
    }
  } else {                              // x: 32x32 tiles, 8(b) x 32(i) grid
    const int t2 = t - 1024;
    const int b0 = (t2 >> 5) * 32, i0 = (t2 & 31) * 32;
#pragma unroll
    for (int k = 0; k < 4; ++k) {
      int idx = tid + k * 256, r = idx >> 5, c = idx & 31;   // r:b c:i
      lt[r][c] = x[(size_t)(b0 + r) * IDIM + i0 + c];
    }
    __syncthreads();
#pragma unroll
    for (int k = 0; k < 4; ++k) {
      int idx = tid + k * 256, il = idx >> 5, bl = idx & 31;  // bl fast: coalesced
      xT[(size_t)(i0 + il) * BDIM + b0 + bl] = lt[bl][il];
    }
  }
}

// ---------------------------------------------------------------------------
// Main: lanes = batch rows; 16 waves x 64-i slices. x in 64 VGPRs (one-time
// coalesced load), w streamed via s_load (wave-uniform). Inner loop is pure
// v_pk_mul / v_exp / v_pk_fma / v_pk_add. ~100 VGPR -> 4 waves/SIMD.
// ---------------------------------------------------------------------------
__global__ __launch_bounds__(1024, 4)
void stl_main(const float* __restrict__ xT, const float* __restrict__ wS,
              const float* __restrict__ bias, float* __restrict__ out) {
  __shared__ float ps[NW2][2 * NO2][64];   // 64 KB, [wave][2o][lane]: conflict-free writes

  const int tx = threadIdx.x;              // 0..63 -> batch row (lane)
  const int ty = threadIdx.y;              // 0..15 -> i-sixteenth (one wave each)
  const int o0 = blockIdx.x * NO2;
  const int b0 = blockIdx.y * 64;
  const int tyu = __builtin_amdgcn_readfirstlane(ty);
  const int qbase = tyu * QL2;

  // One-time: this lane's 64-f32 x slice into registers (coalesced: lane
  // stride 4B in xT rows). Static indices only.
  v2f xv[NP2];
#pragma unroll
  for (int u = 0; u < NP2; ++u) {
    xv[u].x = xT[(size_t)(qbase + 2 * u) * BDIM + b0 + tx];
    xv[u].y = xT[(size_t)(qbase + 2 * u + 1) * BDIM + b0 + tx];
  }

  // Wave-uniform, linearly-consumed w stream (scalarized pointer -> s_load).
  const float* wrow = uptr(wS + (size_t)tyu * (ODIM * QL2) + (size_t)o0 * QL2);

  for (int o = 0; o < NO2; ++o) {
    const float* wr = wrow + (size_t)o * QL2;
    v2f an = {0.f, 0.f}, ad = {0.f, 0.f};
#pragma unroll
    for (int k = 0; k < NP2; ++k) {
      v2f sw;
      sw.x = wr[2 * k];                    // SGPR values
      sw.y = wr[2 * k + 1];
      v2f p = xv[k] * sw;                  // v_pk_mul (p = log2e*z)
      v2f t;
      t.x = FAST_EXP2(__builtin_fabsf(p.x));  // v_exp_f32, abs folded
      t.y = FAST_EXP2(__builtin_fabsf(p.y));
      an += p * t;                         // v_pk_fma
      ad += t;                             // v_pk_add
    }
    ps[ty][2 * o][tx] = an.x + an.y;       // conflict-free (lane-contiguous)
    ps[ty][2 * o + 1][tx] = ad.x + ad.y;
  }
  __syncthreads();

  // Combine across 16 i-waves: threads 0..511 -> (b, o) pairs, out coalesced
  // in 32B segments.
  const int tid = ty * 64 + tx;
  if (tid < 512) {
    const int b = tid >> 3;                // 0..63
    const int op = tid & 7;                // 0..7
    float n = 0.f, d = 0.f;
#pragma unroll
    for (int wv = 0; wv < NW2; ++wv) {
      n += ps[wv][2 * op][b];
      d += ps[wv][2 * op + 1][b];
    }
    const float LN2 = 0.6931471805599453f;
    const float scale = (float)IDIM * LN2;     // undo log2e, apply n=IDIM
    out[(size_t)(b0 + b) * ODIM + o0 + op] = scale * n / d + bias[o0 + op];
  }
}

// ---------------------------------------------------------------------------
// Fallback (proven ~41 us/dispatch) if workspace too small for wS+xT.
// ---------------------------------------------------------------------------
#define NW 8
#define TILE_OL 2
#define TILE_O (64 * TILE_OL)
#define TILE_B 4
#define FQLEN (IDIM / NW)
#define CHUNK 8
#define NCHUNK (FQLEN / CHUNK)

__global__ __launch_bounds__(512, 4)
void stl_old(const float* __restrict__ x, const float* __restrict__ w,
             const float* __restrict__ bias, float* __restrict__ out) {
  __shared__ float xs[TILE_B][IDIM];
  __shared__ float ps[NW][64][16];

  const int tx = threadIdx.x, ty = threadIdx.y;
  const int tid = ty * 64 + tx;
  const int o0 = blockIdx.x * TILE_O;
  const int b0 = blockIdx.y * TILE_B;
  const float LOG2E = 1.4426950408889634f;

#pragma unroll
  for (int k = 0; k < 2; ++k) {
    int f = tid + k * 512, row = f >> 8, col = f & 255;
    float4 v = ((const float4*)(x + (size_t)(b0 + row) * IDIM))[col];
    v.x *= LOG2E; v.y *= LOG2E; v.z *= LOG2E; v.w *= LOG2E;
    ((float4*)(&xs[row][0]))[col] = v;
  }
  __syncthreads();

  const int qbase = ty * FQLEN;
  const float* wp = w + (size_t)qbase * ODIM + o0 + tx;

  v2f an[TILE_OL][TILE_B], ad[TILE_OL][TILE_B];
#pragma unroll
  for (int s = 0; s < TILE_OL; ++s)
#pragma unroll
    for (int r = 0; r < TILE_B; ++r) { an[s][r] = (v2f){0.f, 0.f}; ad[s][r] = (v2f){0.f, 0.f}; }

  v2f wA0[CHUNK / 2], wA1[CHUNK / 2], wB0[CHUNK / 2], wB1[CHUNK / 2];

#define WLOADF(d0_, d1_, cc)                                              \
  {                                                                       \
    const float* wq = wp + (size_t)((cc) * CHUNK) * ODIM;                 \
    _Pragma("unroll")                                                     \
    for (int u = 0; u < CHUNK / 2; ++u) {                                 \
      d0_[u].x = wq[(size_t)(2 * u) * ODIM];                              \
      d0_[u].y = wq[(size_t)(2 * u + 1) * ODIM];                          \
      d1_[u].x = wq[(size_t)(2 * u) * ODIM + 64];                         \
      d1_[u].y = wq[(size_t)(2 * u + 1) * ODIM + 64];                     \
    }                                                                     \
  }

#define ROWPF(acc_n, acc_d, xpair, wpair)                                 \
  {                                                                       \
    v2f p = (xpair) * (wpair);                                            \
    v2f t;                                                                \
    t.x = FAST_EXP2(__builtin_fabsf(p.x));                                \
    t.y = FAST_EXP2(__builtin_fabsf(p.y));                                \
    acc_n += p * t;                                                       \
    acc_d += t;                                                           \
  }

#define LOF(xq) __builtin_shufflevector(xq, xq, 0, 1)
#define HIF(xq) __builtin_shufflevector(xq, xq, 2, 3)

#define COMPUTEF(wc0, wc1, cc)                                            \
  {                                                                       \
    const int jb = qbase + (cc) * CHUNK;                                  \
    _Pragma("unroll")                                                     \
    for (int h = 0; h < 2; ++h) {                                         \
      v4f xq[TILE_B];                                                     \
      _Pragma("unroll")                                                   \
      for (int r = 0; r < TILE_B; ++r)                                    \
        xq[r] = *(const v4f*)(&xs[r][jb + h * 4]);                        \
      _Pragma("unroll")                                                   \
      for (int r = 0; r < TILE_B; ++r) {                                  \
        ROWPF(an[0][r], ad[0][r], LOF(xq[r]), wc0[h * 2])                 \
        ROWPF(an[0][r], ad[0][r], HIF(xq[r]), wc0[h * 2 + 1])             \
        ROWPF(an[1][r], ad[1][r], LOF(xq[r]), wc1[h * 2])                 \
        ROWPF(an[1][r], ad[1][r], HIF(xq[r]), wc1[h * 2 + 1])             \
      }                                                                   \
    }                                                                     \
  }

  WLOADF(wA0, wA1, 0)
  for (int c = 0; c < NCHUNK; c += 2) {
    WLOADF(wB0, wB1, c + 1)
    COMPUTEF(wA0, wA1, c)
    WLOADF(wA0, wA1, (c + 2) & (NCHUNK - 1))
    COMPUTEF(wB0, wB1, c + 1)
  }

#pragma unroll
  for (int s = 0; s < TILE_OL; ++s) {
    *(float4*)(&ps[ty][tx][s * 8 + 0]) =
        make_float4(an[s][0].x + an[s][0].y, an[s][1].x + an[s][1].y,
                    an[s][2].x + an[s][2].y, an[s][3].x + an[s][3].y);
    *(float4*)(&ps[ty][tx][s * 8 + 4]) =
        make_float4(ad[s][0].x + ad[s][0].y, ad[s][1].x + ad[s][1].y,
                    ad[s][2].x + ad[s][2].y, ad[s][3].x + ad[s][3].y);
  }
  __syncthreads();

  if (ty == 0) {
    const float LN2 = 0.6931471805599453f;
    const float scale = (float)IDIM * LN2;
#pragma unroll
    for (int s = 0; s < TILE_OL; ++s) {
      float n[4] = {0, 0, 0, 0}, d[4] = {0, 0, 0, 0};
#pragma unroll
      for (int q = 0; q < NW; ++q) {
        float4 a = *(const float4*)(&ps[q][tx][s * 8 + 0]);
        float4 b2 = *(const float4*)(&ps[q][tx][s * 8 + 4]);
        n[0] += a.x; n[1] += a.y; n[2] += a.z; n[3] += a.w;
        d[0] += b2.x; d[1] += b2.y; d[2] += b2.z; d[3] += b2.w;
      }
      const int o = o0 + tx + s * 64;
      const float bo = bias[o];
#pragma unroll
      for (int r = 0; r < 4; ++r)
        out[(size_t)(b0 + r) * ODIM + o] = scale * n[r] / d[r] + bo;
    }
  }
}

extern "C" void kernel_launch(void* const* d_in, const int* in_sizes, int n_in,
                              void* d_out, int out_size, void* d_ws, size_t ws_size,
                              hipStream_t stream) {
  const float* x = (const float*)d_in[0];    // [256,1024] f32
  const float* w = (const float*)d_in[1];    // [1024,1024] f32
  const float* b = (const float*)d_in[2];    // [1024] f32
  float* out = (float*)d_out;                // [256,1024] f32

  const size_t wS_bytes = (size_t)NW2 * ODIM * QL2 * sizeof(float);  // 4 MB
  const size_t xT_bytes = (size_t)IDIM * BDIM * sizeof(float);       // 1 MB

  if (ws_size >= wS_bytes + xT_bytes) {
    float* wS = (float*)d_ws;
    float* xT = (float*)((char*)d_ws + wS_bytes);
    prep2<<<1280, 256, 0, stream>>>(x, w, wS, xT);
    dim3 grid(ODIM / NO2, BDIM / 64);       // (128, 4) = 512 blocks
    dim3 block(64, NW2);                    // 1024 threads = 16 waves
    stl_main<<<grid, block, 0, stream>>>(xT, wS, b, out);
  } else {
    dim3 grid(ODIM / TILE_O, BDIM / TILE_B);
    dim3 block(64, NW);
    stl_old<<<grid, block, 0, stream>>>(x, w, b, out);
  }
}

// Round 7
// 92.377 us; speedup vs baseline: 1.2629x; 1.2629x over previous
//
#include <hip/hip_runtime.h>

// Problem dims (fixed by reference setup_inputs)
#define BDIM 256
#define IDIM 1024
#define ODIM 1024

#define NW 8                  // waves per block, each owns an i-eighth
#define TILE_OL 2             // output columns per lane
#define TILE_O (64 * TILE_OL) // 128 outputs per block
#define TILE_B 4              // batch rows per thread
#define QLEN (IDIM / NW)      // 128 i per wave
#define CHUNK 8               // i per w-prefetch chunk
#define NCHUNK (QLEN / CHUNK) // 16 chunks

typedef float v2f __attribute__((ext_vector_type(2)));
typedef float v4f __attribute__((ext_vector_type(4)));

#if __has_builtin(__builtin_amdgcn_exp2f)
#define FAST_EXP2(v) __builtin_amdgcn_exp2f(v)
#else
#define FAST_EXP2(v) exp2f(v)
#endif

__global__ __launch_bounds__(512, 4)
void stl_kernel(const float* __restrict__ x,
                const float* __restrict__ w,
                const float* __restrict__ bias,
                float* __restrict__ out) {
  __shared__ float xs[TILE_B][IDIM];    // 16 KB: 4 x rows, prescaled by log2e
  __shared__ float ps[NW][64][16];      // 32 KB: per-wave partials (2 o-sets)

  const int tx = threadIdx.x;           // 0..63 -> output column (lane)
  const int ty = threadIdx.y;           // 0..7  -> i-eighth (one wave each)
  const int tid = ty * 64 + tx;
  const int o0 = blockIdx.x * TILE_O;
  const int b0 = blockIdx.y * TILE_B;

  const float LOG2E = 1.4426950408889634f;  // folds 1/TEMPERATURE too

  // ---- Stage 4 x rows once (coalesced, prescaled). Barrier #1. ----
#pragma unroll
  for (int k = 0; k < 2; ++k) {
    int f = tid + k * 512;              // 0..1023 float4s
    int row = f >> 8;                   // 256 float4 per row
    int col = f & 255;
    float4 v = ((const float4*)(x + (size_t)(b0 + row) * IDIM))[col];
    v.x *= LOG2E; v.y *= LOG2E; v.z *= LOG2E; v.w *= LOG2E;
    ((float4*)(&xs[row][0]))[col] = v;
  }
  __syncthreads();

  const int qbase = ty * QLEN;
  // Lane owns columns o0+tx and o0+tx+64 (+64 is an immediate offset).
  const float* wp = w + (size_t)qbase * ODIM + o0 + tx;

  // Per-wave chunk rotation: wave ty visits its 16 chunks starting at 2*ty.
  // Breaks the cross-wave convoy (aligned VMEM bursts / aligned waits) that
  // r3/r4 counters exposed (63% busy, idle invariant to LDS traffic).
  const int rot = ty * 2;
#define CID(c) ((((c) + rot)) & (NCHUNK - 1))

  // Accumulators: [o-set][batch row], packed over i-pairs -> all v_pk_*.
  v2f an[TILE_OL][TILE_B], ad[TILE_OL][TILE_B];
#pragma unroll
  for (int s = 0; s < TILE_OL; ++s)
#pragma unroll
    for (int r = 0; r < TILE_B; ++r) { an[s][r] = (v2f){0.f, 0.f}; ad[s][r] = (v2f){0.f, 0.f}; }

  // w prefetch depth 2: 3 rotating buffers, loads issued two COMPUTEs ahead.
  // All wbuf indices are compile-time constants after full unroll (rule #20).
  v2f wbuf[3][TILE_OL][CHUNK / 2];

#define WLOADI(bi, cc)                                                    \
  {                                                                       \
    const float* wq = wp + (size_t)((cc) * CHUNK) * ODIM;                 \
    _Pragma("unroll")                                                     \
    for (int u = 0; u < CHUNK / 2; ++u) {                                 \
      wbuf[bi][0][u].x = wq[(size_t)(2 * u) * ODIM];                      \
      wbuf[bi][0][u].y = wq[(size_t)(2 * u + 1) * ODIM];                  \
      wbuf[bi][1][u].x = wq[(size_t)(2 * u) * ODIM + 64];                 \
      wbuf[bi][1][u].y = wq[(size_t)(2 * u + 1) * ODIM + 64];             \
    }                                                                     \
  }

#define ROWPF(acc_n, acc_d, xpair, wpair)                                 \
  {                                                                       \
    v2f p = (xpair) * (wpair);          /* v_pk_mul (p = log2e*z) */      \
    v2f t;                                                                \
    t.x = FAST_EXP2(__builtin_fabsf(p.x));  /* v_exp_f32, abs folded */   \
    t.y = FAST_EXP2(__builtin_fabsf(p.y));                                \
    acc_n += p * t;                     /* v_pk_fma */                    \
    acc_d += t;                         /* v_pk_add */                    \
  }

#define LOF(xq) __builtin_shufflevector(xq, xq, 0, 1)
#define HIF(xq) __builtin_shufflevector(xq, xq, 2, 3)

#define COMPUTEI(bi, cc)                                                  \
  {                                                                       \
    const int jb = qbase + (cc) * CHUNK;                                  \
    _Pragma("unroll")                                                     \
    for (int h = 0; h < 2; ++h) {                                         \
      v4f xq[TILE_B];                                                     \
      _Pragma("unroll")                                                   \
      for (int r = 0; r < TILE_B; ++r)                                    \
        xq[r] = *(const v4f*)(&xs[r][jb + h * 4]);                        \
      _Pragma("unroll")                                                   \
      for (int r = 0; r < TILE_B; ++r) {                                  \
        ROWPF(an[0][r], ad[0][r], LOF(xq[r]), wbuf[bi][0][h * 2])         \
        ROWPF(an[0][r], ad[0][r], HIF(xq[r]), wbuf[bi][0][h * 2 + 1])     \
        ROWPF(an[1][r], ad[1][r], LOF(xq[r]), wbuf[bi][1][h * 2])         \
        ROWPF(an[1][r], ad[1][r], HIF(xq[r]), wbuf[bi][1][h * 2 + 1])     \
      }                                                                   \
    }                                                                     \
  }

  // ---- Main loop, fully unrolled: depth-2 software pipeline. ----
  WLOADI(0, CID(0))
  WLOADI(1, CID(1))
#pragma unroll
  for (int c = 0; c < NCHUNK; ++c) {
    if (c + 2 < NCHUNK) WLOADI((c + 2) % 3, CID(c + 2))
    COMPUTEI(c % 3, CID(c))
  }

  // ---- Cross-wave combine (barrier #2) ----
#pragma unroll
  for (int s = 0; s < TILE_OL; ++s) {
    *(float4*)(&ps[ty][tx][s * 8 + 0]) =
        make_float4(an[s][0].x + an[s][0].y, an[s][1].x + an[s][1].y,
                    an[s][2].x + an[s][2].y, an[s][3].x + an[s][3].y);
    *(float4*)(&ps[ty][tx][s * 8 + 4]) =
        make_float4(ad[s][0].x + ad[s][0].y, ad[s][1].x + ad[s][1].y,
                    ad[s][2].x + ad[s][2].y, ad[s][3].x + ad[s][3].y);
  }
  __syncthreads();

  if (ty == 0) {
    const float LN2 = 0.6931471805599453f;
    const float scale = (float)IDIM * LN2;    // undo log2e, apply n=IDIM
#pragma unroll
    for (int s = 0; s < TILE_OL; ++s) {
      float n[4] = {0, 0, 0, 0}, d[4] = {0, 0, 0, 0};
#pragma unroll
      for (int q = 0; q < NW; ++q) {
        float4 a = *(const float4*)(&ps[q][tx][s * 8 + 0]);
        float4 b2 = *(const float4*)(&ps[q][tx][s * 8 + 4]);
        n[0] += a.x; n[1] += a.y; n[2] += a.z; n[3] += a.w;
        d[0] += b2.x; d[1] += b2.y; d[2] += b2.z; d[3] += b2.w;
      }
      const int o = o0 + tx + s * 64;
      const float bo = bias[o];
#pragma unroll
      for (int r = 0; r < 4; ++r)
        out[(size_t)(b0 + r) * ODIM + o] = scale * n[r] / d[r] + bo;
    }
  }
}

extern "C" void kernel_launch(void* const* d_in, const int* in_sizes, int n_in,
                              void* d_out, int out_size, void* d_ws, size_t ws_size,
                              hipStream_t stream) {
  const float* x = (const float*)d_in[0];    // [256,1024] f32
  const float* w = (const float*)d_in[1];    // [1024,1024] f32
  const float* b = (const float*)d_in[2];    // [1024] f32
  float* out = (float*)d_out;                // [256,1024] f32

  dim3 grid(ODIM / TILE_O, BDIM / TILE_B);   // (8, 64) = 512 blocks = 2/CU
  dim3 block(64, NW);                        // 512 threads = 8 waves
  stl_kernel<<<grid, block, 0, stream>>>(x, w, b, out);
}